// Round 13
// baseline (264.483 us; speedup 1.0000x reference)
//
#include <hip/hip_runtime.h>
#include <hip/hip_bf16.h>

typedef __bf16 bf16_t;
typedef __bf16 bf16x4 __attribute__((ext_vector_type(4)));
typedef __bf16 bf16x8 __attribute__((ext_vector_type(8)));
typedef float f32x4 __attribute__((ext_vector_type(4)));

#define Bb 4
#define Ss 2048
#define Dd 1024
#define Hh 16
#define HDd 64

// attention scale folded into Q at GEMM1 epilogue: 1/8 * log2(e)
#define QSC 0.1803368801111244f

// async global->LDS, 16B per lane. LDS dest must be wave-uniform base + lane*16.
__device__ __forceinline__ void gld16(const bf16_t* g, bf16_t* l) {
  __builtin_amdgcn_global_load_lds(
      (const __attribute__((address_space(1))) unsigned int*)g,
      (__attribute__((address_space(3))) unsigned int*)l, 16, 0, 0);
}

// ---------------------------------------------------------------- prep
// Fused: conv_to_bf16 (blocks 0..8191) + w_qkv transpose (blocks 8192..11263).
__global__ __launch_bounds__(256) void prep(
    const float* __restrict__ x, bf16_t* __restrict__ Xc,
    const float* __restrict__ w_qkv, bf16_t* __restrict__ Wt1) {
  __shared__ bf16_t tile[32][33];
  const int b = blockIdx.x;
  const int tid = threadIdx.x;
  if (b < 8192) {
    int i = (b * 256 + tid) * 4;
    float4 v = *(const float4*)&x[i];
    bf16x4 o = {(bf16_t)v.x, (bf16_t)v.y, (bf16_t)v.z, (bf16_t)v.w};
    *(bf16x4*)&Xc[i] = o;
  } else {
    const int id = b - 8192;           // 0..3071 = 96 x 32 tiles
    const int c0 = (id % 96) * 32, r0 = (id / 96) * 32;
    const int tx = tid & 31, ty = tid >> 5;   // 32 x 8
#pragma unroll
    for (int j = 0; j < 32; j += 8)
      tile[ty + j][tx] = (bf16_t)w_qkv[(size_t)(r0 + ty + j) * 3072 + c0 + tx];
    __syncthreads();
#pragma unroll
    for (int j = 0; j < 32; j += 8)
      Wt1[(size_t)(c0 + ty + j) * 1024 + r0 + tx] = tile[tx][ty + j];
  }
}

// ---------------------------------------------------------------- transpose
__global__ __launch_bounds__(256) void transpose_conv(
    const float* __restrict__ in, bf16_t* __restrict__ out, int R, int C) {
  __shared__ bf16_t tile[32][33];
  int c0 = blockIdx.x * 32, r0 = blockIdx.y * 32;
  int tx = threadIdx.x, ty = threadIdx.y;  // 32 x 8
#pragma unroll
  for (int j = 0; j < 32; j += 8)
    tile[ty + j][tx] = (bf16_t)in[(size_t)(r0 + ty + j) * C + c0 + tx];
  __syncthreads();
#pragma unroll
  for (int j = 0; j < 32; j += 8)
    out[(size_t)(c0 + ty + j) * R + r0 + tx] = tile[tx][ty + j];
}

// ---------------------------------------------------------------- GEMM wide
// UNDER TEST: per-wave 128x64 output (0.375 ds_read/MFMA vs 0.5 in all four
// 22-27% MfmaUtil structures measured so far; m201's 62% config uses this).
// BM=256, BN=256, BK=32; 4-slot LDS ring (128 KiB); 512 threads = 8 waves
// (2M x 4N), per-wave 128x64 = 8x4 frags, 32 MFMA per K-tile.
// Per K-tile: 2 phases. ph0: {4 B-frags + 4 A-frags (m0-3), stageA(t+2),
// barrier, lgkm0, prio1, 16 MFMA, prio0, barrier}. ph1: {4 A-frags (m4-7),
// stageB(t+2), barrier, lgkm0, prio1, 16 MFMA, prio0, boundary}.
// Ledger: 4 loads/tile (2A+2B). At boundary of t: outstanding = t+1(4) +
// t+2(4, newest); vmcnt(4) -> t+1 landed, t+2 in flight. vmcnt(0) only when
// no stage issued. Ring-4 safety: slot (t+2)&3 last read at t-2, done before
// end-of-(t-2) barrier; stage issued after end-of-(t-1) barrier.
// Swizzle (K=32): row = 64B = 4x16B chunks; logical chunk = quad (one frag
// = full K); stored chunk = quad ^ ((row>>1)&3); pre-swizzled global source.
// Lanes 0-15 of a quad: 8 distinct (row-parity, chunk) positions x2 -> 2-way
// max (free, m136).
template <int MODE>
__global__ __launch_bounds__(512, 2) void gemm_wide(
    const bf16_t* __restrict__ A, const bf16_t* __restrict__ Bt,
    const float* __restrict__ bias, float* __restrict__ outf,
    bf16_t* __restrict__ out0, bf16_t* __restrict__ out1,
    bf16_t* __restrict__ out2, int M, int N, int K) {
  const int tid = threadIdx.x;        // 0..511
  const int lane = tid & 63;
  const int wave = tid >> 6;          // 0..7
  const int quad = lane >> 4;
  const int lr = lane & 15;
  const int wr = wave >> 2;           // 0..1 (M half, 128 rows)
  const int wc = wave & 3;            // 0..3 (N quarter, 64 cols)
  const int m0 = blockIdx.y * 256;
  const int n0 = blockIdx.x * 256;

  __shared__ __align__(16) bf16_t As[4][256 * 32];  // 64 KiB
  __shared__ __align__(16) bf16_t Bs[4][256 * 32];  // 64 KiB

  const f32x4 zero = {0.f, 0.f, 0.f, 0.f};
  f32x4 acc[8][4];
#pragma unroll
  for (int mi = 0; mi < 8; ++mi)
#pragma unroll
    for (int ni = 0; ni < 4; ++ni) acc[mi][ni] = zero;

  // staging map: chunk c (0..1023): row=c>>2, q=c&3; src chunk q^((row>>1)&3).
  int sr[2], sc[2];
#pragma unroll
  for (int i = 0; i < 2; ++i) {
    int c = tid + i * 512;
    sr[i] = c >> 2;
    sc[i] = ((c & 3) ^ ((sr[i] >> 1) & 3)) * 8;
  }

  const int nk = K >> 5;

  auto stageA = [&](int t, int s) {
    const int ko = t << 5;
#pragma unroll
    for (int i = 0; i < 2; ++i)
      gld16(&A[(size_t)(m0 + sr[i]) * K + ko + sc[i]],
            &As[s][(tid + i * 512) * 8]);
  };
  auto stageB = [&](int t, int s) {
    const int ko = t << 5;
#pragma unroll
    for (int i = 0; i < 2; ++i)
      gld16(&Bt[(size_t)(n0 + sr[i]) * K + ko + sc[i]],
            &Bs[s][(tid + i * 512) * 8]);
  };

  // prologue: tiles 0,1 in flight (8 loads); tile 0 = oldest 4.
  stageA(0, 0); stageB(0, 0);
  stageA(1, 1); stageB(1, 1);
  asm volatile("s_waitcnt vmcnt(4)" ::: "memory");
  __builtin_amdgcn_s_barrier();

  const int cx = (quad ^ ((lr >> 1) & 3)) * 8;  // stored chunk * 8 elems
  const int abase = wr * 128 + lr;              // + mi*16
  const int bbase = wc * 64 + lr;               // + ni*16

  for (int t = 0; t < nk; ++t) {
    const bf16_t* as = As[t & 3];
    const bf16_t* bs = Bs[t & 3];
    const int s2 = (t + 2) & 3;
    const bool pre = (t + 2 < nk);
    bf16x8 af[4], bfr[4];
    // ---- phase 0: B-frags + A m0..3, stage A(t+2), 16 MFMA
#pragma unroll
    for (int ni = 0; ni < 4; ++ni)
      bfr[ni] = *(const bf16x8*)&bs[(bbase + ni * 16) * 32 + cx];
#pragma unroll
    for (int mi = 0; mi < 4; ++mi)
      af[mi] = *(const bf16x8*)&as[(abase + mi * 16) * 32 + cx];
    if (pre) stageA(t + 2, s2);
    __builtin_amdgcn_s_barrier();
    asm volatile("s_waitcnt lgkmcnt(0)" ::: "memory");
    __builtin_amdgcn_sched_barrier(0);
    __builtin_amdgcn_s_setprio(1);
#pragma unroll
    for (int mi = 0; mi < 4; ++mi)
#pragma unroll
      for (int ni = 0; ni < 4; ++ni)
        acc[mi][ni] = __builtin_amdgcn_mfma_f32_16x16x32_bf16(
            af[mi], bfr[ni], acc[mi][ni], 0, 0, 0);
    __builtin_amdgcn_s_setprio(0);
    __builtin_amdgcn_s_barrier();
    // ---- phase 1: A m4..7 (B reused), stage B(t+2), 16 MFMA
#pragma unroll
    for (int mi = 0; mi < 4; ++mi)
      af[mi] = *(const bf16x8*)&as[(abase + (mi + 4) * 16) * 32 + cx];
    if (pre) stageB(t + 2, s2);
    __builtin_amdgcn_s_barrier();
    asm volatile("s_waitcnt lgkmcnt(0)" ::: "memory");
    __builtin_amdgcn_sched_barrier(0);
    __builtin_amdgcn_s_setprio(1);
#pragma unroll
    for (int mi = 0; mi < 4; ++mi)
#pragma unroll
      for (int ni = 0; ni < 4; ++ni)
        acc[mi + 4][ni] = __builtin_amdgcn_mfma_f32_16x16x32_bf16(
            af[mi], bfr[ni], acc[mi + 4][ni], 0, 0, 0);
    __builtin_amdgcn_s_setprio(0);
    if (t + 1 < nk) {
      if (pre)
        asm volatile("s_waitcnt vmcnt(4)" ::: "memory");
      else
        asm volatile("s_waitcnt vmcnt(0)" ::: "memory");
      __builtin_amdgcn_s_barrier();
    }
  }

  // Epilogue. C/D layout: col = lane&15, row = quad*4 + r.
#pragma unroll
  for (int mi = 0; mi < 8; ++mi) {
    const int mbase = m0 + wr * 128 + mi * 16 + quad * 4;
#pragma unroll
    for (int ni = 0; ni < 4; ++ni) {
      const int n = n0 + wc * 64 + ni * 16 + lr;
      const float bv = bias[n];
      if (MODE == 1) {
#pragma unroll
        for (int r = 0; r < 4; ++r)
          outf[(size_t)(mbase + r) * N + n] = acc[mi][ni][r] + bv;
      } else {
        const int which = n >> 10;      // uniform per block (256 | 1024)
        const int h = (n >> 6) & 15;
        const int hd = n & 63;
        const int b = mbase >> 11;
        const int s = mbase & 2047;
        if (which == 2) {
          bf16x4 pk = {(bf16_t)(acc[mi][ni][0] + bv),
                       (bf16_t)(acc[mi][ni][1] + bv),
                       (bf16_t)(acc[mi][ni][2] + bv),
                       (bf16_t)(acc[mi][ni][3] + bv)};
          *(bf16x4*)&out2[(((size_t)(b * Hh + h)) * HDd + hd) * Ss + s] = pk;
        } else {
          bf16_t* dst = (which == 0) ? out0 : out1;
          const float sc2 = (which == 0) ? QSC : 1.0f;
#pragma unroll
          for (int r = 0; r < 4; ++r)
            dst[(((size_t)(b * Hh + h)) * Ss + s + r) * HDd + hd] =
                (bf16_t)((acc[mi][ni][r] + bv) * sc2);
        }
      }
    }
  }
}

// ---------------------------------------------------------------- GEMM 8-phase (kept for GEMM2: N=1024 grid 256 exact)
template <int MODE>
__global__ __launch_bounds__(512, 2) void gemm_8p(
    const bf16_t* __restrict__ A, const bf16_t* __restrict__ Bt,
    const float* __restrict__ bias, float* __restrict__ outf,
    bf16_t* __restrict__ out0, bf16_t* __restrict__ out1,
    bf16_t* __restrict__ out2, int M, int N, int K) {
  const int tid = threadIdx.x;        // 0..511
  const int lane = tid & 63;
  const int wave = tid >> 6;          // 0..7
  const int quad = lane >> 4;
  const int lr = lane & 15;
  const int wr = wave >> 1;           // 0..3 (M quarter, 64 rows)
  const int wc = wave & 1;            // 0..1 (N half, 64 cols)
  const int m0 = blockIdx.y * 256;
  const int n0 = blockIdx.x * 128;

  __shared__ __align__(16) bf16_t As[3][256 * 64];  // 96 KiB
  __shared__ __align__(16) bf16_t Bs[3][128 * 64];  // 48 KiB

  const f32x4 zero = {0.f, 0.f, 0.f, 0.f};
  f32x4 acc[4][4];
#pragma unroll
  for (int mi = 0; mi < 4; ++mi)
#pragma unroll
    for (int ni = 0; ni < 4; ++ni) acc[mi][ni] = zero;

  int ar[4], ac[4], br[2], bc[2];
#pragma unroll
  for (int i = 0; i < 4; ++i) {
    int c = tid + i * 512;
    ar[i] = c >> 3;
    ac[i] = ((c & 7) ^ (ar[i] & 7)) * 8;
  }
#pragma unroll
  for (int i = 0; i < 2; ++i) {
    int c = tid + i * 512;
    br[i] = c >> 3;
    bc[i] = ((c & 7) ^ (br[i] & 7)) * 8;
  }

  const int nk = K >> 6;

  auto stageA = [&](int t, int s) {
    const int ko = t << 6;
#pragma unroll
    for (int i = 0; i < 4; ++i)
      gld16(&A[(size_t)(m0 + ar[i]) * K + ko + ac[i]],
            &As[s][(tid + i * 512) * 8]);
  };
  auto stageB = [&](int t, int s) {
    const int ko = t << 6;
#pragma unroll
    for (int i = 0; i < 2; ++i)
      gld16(&Bt[(size_t)(n0 + br[i]) * K + ko + bc[i]],
            &Bs[s][(tid + i * 512) * 8]);
  };

  stageA(0, 0); stageB(0, 0);
  stageA(1, 1); stageB(1, 1);
  asm volatile("s_waitcnt vmcnt(6)" ::: "memory");
  __builtin_amdgcn_s_barrier();

  const int sx = lr & 7;
  const int arow = wr * 64 + lr;
  const int brow = wc * 64 + lr;

  int scur = 0;
  for (int t = 0; t < nk; ++t) {
    const bf16_t* as = As[scur];
    const bf16_t* bs = Bs[scur];
    int s2 = scur + 2;
    if (s2 >= 3) s2 -= 3;
    const bool pre = (t + 2 < nk);
#pragma unroll
    for (int ks = 0; ks < 2; ++ks) {
      bf16x8 af[4], bfr[4];
      const int cx = (((ks << 2) | quad) ^ sx) * 8;
#pragma unroll
      for (int mi = 0; mi < 4; ++mi)
        af[mi] = *(const bf16x8*)&as[(arow + mi * 16) * 64 + cx];
#pragma unroll
      for (int ni = 0; ni < 4; ++ni)
        bfr[ni] = *(const bf16x8*)&bs[(brow + ni * 16) * 64 + cx];
      if (ks == 0) {
        if (pre) stageA(t + 2, s2);
      } else {
        if (pre) stageB(t + 2, s2);
      }
      __builtin_amdgcn_s_barrier();
      asm volatile("s_waitcnt lgkmcnt(0)" ::: "memory");
      __builtin_amdgcn_sched_barrier(0);
      __builtin_amdgcn_s_setprio(1);
#pragma unroll
      for (int mi = 0; mi < 4; ++mi)
#pragma unroll
        for (int ni = 0; ni < 4; ++ni)
          acc[mi][ni] = __builtin_amdgcn_mfma_f32_16x16x32_bf16(
              af[mi], bfr[ni], acc[mi][ni], 0, 0, 0);
      __builtin_amdgcn_s_setprio(0);
      if (ks == 0) {
        __builtin_amdgcn_s_barrier();
      } else if (t + 1 < nk) {
        if (pre)
          asm volatile("s_waitcnt vmcnt(6)" ::: "memory");
        else
          asm volatile("s_waitcnt vmcnt(0)" ::: "memory");
        __builtin_amdgcn_s_barrier();
      }
    }
    scur = (scur == 2) ? 0 : scur + 1;
  }

#pragma unroll
  for (int mi = 0; mi < 4; ++mi) {
    const int mbase = m0 + wr * 64 + mi * 16 + quad * 4;
#pragma unroll
    for (int ni = 0; ni < 4; ++ni) {
      const int n = n0 + wc * 64 + ni * 16 + lr;
      const float bv = bias[n];
      if (MODE == 1) {
#pragma unroll
        for (int r = 0; r < 4; ++r)
          outf[(size_t)(mbase + r) * N + n] = acc[mi][ni][r] + bv;
      } else {
        const int which = n >> 10;
        const int h = (n >> 6) & 15;
        const int hd = n & 63;
        const int b = mbase >> 11;
        const int s = mbase & 2047;
        if (which == 2) {
          bf16x4 pk = {(bf16_t)(acc[mi][ni][0] + bv),
                       (bf16_t)(acc[mi][ni][1] + bv),
                       (bf16_t)(acc[mi][ni][2] + bv),
                       (bf16_t)(acc[mi][ni][3] + bv)};
          *(bf16x4*)&out2[(((size_t)(b * Hh + h)) * HDd + hd) * Ss + s] = pk;
        } else {
          bf16_t* dst = (which == 0) ? out0 : out1;
          const float sc2 = (which == 0) ? QSC : 1.0f;
#pragma unroll
          for (int r = 0; r < 4; ++r)
            dst[(((size_t)(b * Hh + h)) * Ss + s + r) * HDd + hd] =
                (bf16_t)((acc[mi][ni][r] + bv) * sc2);
        }
      }
    }
  }
}

// ---------------------------------------------------------------- attention
// r11 version (best measured attn path): swizzled LDS + VALU l_run + shfl
// reduce. r12's l-via-MFMA REVERTED (within-round A/B: +1.6us — the 4 extra
// MFMAs sit on the serial QK->softmax->PV chain; VALUBusy unchanged, so the
// l-adds were never the VALU cost. exp2+cvt are.)
__global__ __launch_bounds__(256) void attn_kernel(
    const bf16_t* __restrict__ Qg, const bf16_t* __restrict__ Kg,
    const bf16_t* __restrict__ Vtg, bf16_t* __restrict__ Og) {
  const int tid = threadIdx.x;
  const int lane = tid & 63;
  const int wave = tid >> 6;
  const int quad = lane >> 4;
  const int lr = lane & 15;
  const int l7 = lr & 7;

  const int bid = blockIdx.x;        // 0..511
  const int xcd = bid & 7;
  const int j = bid >> 3;            // 0..63
  const int bh = xcd * 8 + (j >> 3); // 8 bh per XCD
  const int p = j & 7;               // pair index 0..7
  const int b = bh >> 4;
  const int h = bh & 15;
  const int wq = wave * 32;

  const bf16_t* Qp = Qg + (size_t)bh * Ss * HDd;   // [s][d] (pre-scaled)
  const bf16_t* Kp = Kg + (size_t)bh * Ss * HDd;   // [s][d]
  const bf16_t* Vp = Vtg + (size_t)bh * HDd * Ss;  // [d][s]

  __shared__ bf16_t Ks[2][64 * 64];    // [buf][key][d]   swizzled rows
  __shared__ bf16_t Vts[2][64 * 64];   // [buf][d][key]   swizzled rows
  __shared__ bf16_t Ps[4][32 * 64];    // per-wave P [q][key] swizzled rows

  bf16x8 kreg[2], vreg[2];
  const int r0 = tid >> 3;             // 0..31
  const int c0 = (tid & 7) * 8;        // 0..56
  const int swz = ((tid & 7) ^ ((tid >> 3) & 7)) * 8;

  const f32x4 zero = {0.f, 0.f, 0.f, 0.f};

#pragma unroll
  for (int i = 0; i < 2; ++i) {
    kreg[i] = *(const bf16x8*)&Kp[(size_t)(r0 + i * 32) * HDd + c0];
    vreg[i] = *(const bf16x8*)&Vp[(size_t)(r0 + i * 32) * Ss + c0];
  }

  int cur = 0;
  for (int half = 0; half < 2; ++half) {
    const int qt = half ? p : 15 - p;
    const int qbase = qt * 128;
    const int ktiles = qt * 2 + 2;

    bf16x8 bq[2][2];
#pragma unroll
    for (int qt2 = 0; qt2 < 2; ++qt2)
#pragma unroll
      for (int kk2 = 0; kk2 < 2; ++kk2)
        bq[qt2][kk2] = *(const bf16x8*)&Qp[(size_t)(qbase + wq + qt2 * 16 +
                                                    lr) *
                                               HDd +
                                           kk2 * 32 + quad * 8];

    f32x4 oacc[4][2];
#pragma unroll
    for (int dt = 0; dt < 4; ++dt)
#pragma unroll
      for (int qt2 = 0; qt2 < 2; ++qt2) oacc[dt][qt2] = zero;
    float l_run[2] = {0.f, 0.f};

    for (int kt = 0; kt < ktiles; ++kt) {
      const int kbase = kt * 64;

#pragma unroll
      for (int i = 0; i < 2; ++i) {
        *(bf16x8*)&Ks[cur][(r0 + i * 32) * 64 + swz] = kreg[i];
        *(bf16x8*)&Vts[cur][(r0 + i * 32) * 64 + swz] = vreg[i];
      }
      __syncthreads();

      const int nkb = (kt + 1 < ktiles) ? kbase + 64 : 0;
#pragma unroll
      for (int i = 0; i < 2; ++i) {
        kreg[i] = *(const bf16x8*)&Kp[(size_t)(nkb + r0 + i * 32) * HDd + c0];
        vreg[i] = *(const bf16x8*)&Vp[(size_t)(r0 + i * 32) * Ss + nkb + c0];
      }

      f32x4 sacc[4][2];
#pragma unroll
      for (int kt4 = 0; kt4 < 4; ++kt4)
#pragma unroll
        for (int qt2 = 0; qt2 < 2; ++qt2) sacc[kt4][qt2] = zero;
#pragma unroll
      for (int kk2 = 0; kk2 < 2; ++kk2) {
        const int rsl = (((kk2 << 2) | quad) ^ l7) * 8;
        bf16x8 ak[4];
#pragma unroll
        for (int kt4 = 0; kt4 < 4; ++kt4)
          ak[kt4] = *(const bf16x8*)&Ks[cur][(kt4 * 16 + lr) * 64 + rsl];
#pragma unroll
        for (int kt4 = 0; kt4 < 4; ++kt4)
#pragma unroll
          for (int qt2 = 0; qt2 < 2; ++qt2)
            sacc[kt4][qt2] = __builtin_amdgcn_mfma_f32_16x16x32_bf16(
                ak[kt4], bq[qt2][kk2], sacc[kt4][qt2], 0, 0, 0);
      }

      const bool edge = (kt >= 2 * qt);
#pragma unroll
      for (int kt4 = 0; kt4 < 4; ++kt4)
#pragma unroll
        for (int qt2 = 0; qt2 < 2; ++qt2)
#pragma unroll
          for (int r = 0; r < 4; ++r) {
            float s = sacc[kt4][qt2][r];
            if (edge) {
              const int qg = qbase + wq + qt2 * 16 + lr;
              const int kg = kbase + kt4 * 16 + quad * 4 + r;
              if (kg > qg) s = -1e30f;
            }
            const float pv = __builtin_amdgcn_exp2f(s);
            sacc[kt4][qt2][r] = pv;
            l_run[qt2] += pv;
          }

#pragma unroll
      for (int kt4 = 0; kt4 < 4; ++kt4) {
        const int psl = ((kt4 * 2 + (quad >> 1)) ^ l7) * 8 + (quad & 1) * 4;
#pragma unroll
        for (int qt2 = 0; qt2 < 2; ++qt2) {
          bf16x4 pk = {(bf16_t)sacc[kt4][qt2][0], (bf16_t)sacc[kt4][qt2][1],
                       (bf16_t)sacc[kt4][qt2][2], (bf16_t)sacc[kt4][qt2][3]};
          *(bf16x4*)&Ps[wave][(qt2 * 16 + lr) * 64 + psl] = pk;
        }
      }

#pragma unroll
      for (int kk2 = 0; kk2 < 2; ++kk2) {
        const int rsl = (((kk2 << 2) | quad) ^ l7) * 8;
        bf16x8 av[4], bp[2];
#pragma unroll
        for (int dt = 0; dt < 4; ++dt)
          av[dt] = *(const bf16x8*)&Vts[cur][(dt * 16 + lr) * 64 + rsl];
#pragma unroll
        for (int qt2 = 0; qt2 < 2; ++qt2)
          bp[qt2] = *(const bf16x8*)&Ps[wave][(qt2 * 16 + lr) * 64 + rsl];
#pragma unroll
        for (int dt = 0; dt < 4; ++dt)
#pragma unroll
          for (int qt2 = 0; qt2 < 2; ++qt2)
            oacc[dt][qt2] = __builtin_amdgcn_mfma_f32_16x16x32_bf16(
                av[dt], bp[qt2], oacc[dt][qt2], 0, 0, 0);
      }
      cur ^= 1;
    }

#pragma unroll
    for (int qt2 = 0; qt2 < 2; ++qt2) {
      l_run[qt2] += __shfl_xor(l_run[qt2], 16, 64);
      l_run[qt2] += __shfl_xor(l_run[qt2], 32, 64);
    }

#pragma unroll
    for (int qt2 = 0; qt2 < 2; ++qt2) {
      const float inv = 1.f / l_run[qt2];
      const int qg = qbase + wq + qt2 * 16 + lr;
#pragma unroll
      for (int dt = 0; dt < 4; ++dt) {
        bf16x4 ov = {(bf16_t)(oacc[dt][qt2][0] * inv),
                     (bf16_t)(oacc[dt][qt2][1] * inv),
                     (bf16_t)(oacc[dt][qt2][2] * inv),
                     (bf16_t)(oacc[dt][qt2][3] * inv)};
        *(bf16x4*)&Og[((size_t)b * Ss + qg) * Dd + h * HDd + dt * 16 +
                      quad * 4] = ov;
      }
    }
  }
}

// ---------------------------------------------------------------- launch
extern "C" void kernel_launch(void* const* d_in, const int* in_sizes, int n_in,
                              void* d_out, int out_size, void* d_ws,
                              size_t ws_size, hipStream_t stream) {
  const float* x = (const float*)d_in[0];       // [4,2048,1024] fp32
  const float* w_qkv = (const float*)d_in[1];   // [1024,3072]
  const float* b_qkv = (const float*)d_in[2];   // [3072]
  const float* w_out = (const float*)d_in[3];   // [1024,1024]
  const float* b_out = (const float*)d_in[4];   // [1024]
  float* out = (float*)d_out;                   // [4,2048,1024] fp32 (32 MB)

  bf16_t* Kb = (bf16_t*)d_ws;                    // [B,H,S,HD]
  bf16_t* Vt = Kb + (size_t)Bb * Hh * Ss * HDd;  // [B,H,HD,S]
  bf16_t* slot3 = Vt + (size_t)Bb * Hh * Ss * HDd;
  bf16_t* Wt1 = slot3;                           // [3072,1024] 6 MB
  bf16_t* Ob = slot3;                            // [8192,1024] 16 MB
  bf16_t* Wt2 = Kb;                              // [1024,1024] 2 MB
  bf16_t* Qb = (bf16_t*)d_out;                   // [B,H,S,HD]
  bf16_t* Xc = (bf16_t*)d_out + (size_t)8192 * 1024;  // [8192,1024] bf16

  // fused conv + w_qkv transpose (8192 + 3072 blocks)
  prep<<<11264, 256, 0, stream>>>(x, Xc, w_qkv, Wt1);

  // GEMM1: 12x32 = 384 blocks of 256x256 (1 block/CU, 128 KiB LDS).
  gemm_wide<0><<<dim3(12, 32), 512, 0, stream>>>(
      Xc, Wt1, b_qkv, nullptr, Qb, Kb, Vt, 8192, 3072, 1024);

  attn_kernel<<<dim3(512), 256, 0, stream>>>(Qb, Kb, Vt, Ob);

  transpose_conv<<<dim3(32, 32), dim3(32, 8), 0, stream>>>(w_out, Wt2, 1024,
                                                           1024);

  // GEMM2: 8x32 = 256 blocks = 1 per CU, uniform single round.
  gemm_8p<1><<<dim3(8, 32), 512, 0, stream>>>(
      Ob, Wt2, b_out, out, nullptr, nullptr, nullptr, 8192, 1024, 1024);
}

// Round 14
// 251.567 us; speedup vs baseline: 1.0513x; 1.0513x over previous
//
#include <hip/hip_runtime.h>
#include <hip/hip_bf16.h>

typedef __bf16 bf16_t;
typedef __bf16 bf16x4 __attribute__((ext_vector_type(4)));
typedef __bf16 bf16x8 __attribute__((ext_vector_type(8)));
typedef float f32x4 __attribute__((ext_vector_type(4)));

#define Bb 4
#define Ss 2048
#define Dd 1024
#define Hh 16
#define HDd 64

// attention scale folded into Q at GEMM1 epilogue: 1/8 * log2(e)
#define QSC 0.1803368801111244f

// async global->LDS, 16B per lane. LDS dest must be wave-uniform base + lane*16.
__device__ __forceinline__ void gld16(const bf16_t* g, bf16_t* l) {
  __builtin_amdgcn_global_load_lds(
      (const __attribute__((address_space(1))) unsigned int*)g,
      (__attribute__((address_space(3))) unsigned int*)l, 16, 0, 0);
}

// ---------------------------------------------------------------- prep
// Fused: conv_to_bf16 (blocks 0..8191) + w_qkv transpose (blocks 8192..11263).
__global__ __launch_bounds__(256) void prep(
    const float* __restrict__ x, bf16_t* __restrict__ Xc,
    const float* __restrict__ w_qkv, bf16_t* __restrict__ Wt1) {
  __shared__ bf16_t tile[32][33];
  const int b = blockIdx.x;
  const int tid = threadIdx.x;
  if (b < 8192) {
    int i = (b * 256 + tid) * 4;
    float4 v = *(const float4*)&x[i];
    bf16x4 o = {(bf16_t)v.x, (bf16_t)v.y, (bf16_t)v.z, (bf16_t)v.w};
    *(bf16x4*)&Xc[i] = o;
  } else {
    const int id = b - 8192;           // 0..3071 = 96 x 32 tiles
    const int c0 = (id % 96) * 32, r0 = (id / 96) * 32;
    const int tx = tid & 31, ty = tid >> 5;   // 32 x 8
#pragma unroll
    for (int j = 0; j < 32; j += 8)
      tile[ty + j][tx] = (bf16_t)w_qkv[(size_t)(r0 + ty + j) * 3072 + c0 + tx];
    __syncthreads();
#pragma unroll
    for (int j = 0; j < 32; j += 8)
      Wt1[(size_t)(c0 + ty + j) * 1024 + r0 + tx] = tile[tx][ty + j];
  }
}

// ---------------------------------------------------------------- transpose
__global__ __launch_bounds__(256) void transpose_conv(
    const float* __restrict__ in, bf16_t* __restrict__ out, int R, int C) {
  __shared__ bf16_t tile[32][33];
  int c0 = blockIdx.x * 32, r0 = blockIdx.y * 32;
  int tx = threadIdx.x, ty = threadIdx.y;  // 32 x 8
#pragma unroll
  for (int j = 0; j < 32; j += 8)
    tile[ty + j][tx] = (bf16_t)in[(size_t)(r0 + ty + j) * C + c0 + tx];
  __syncthreads();
#pragma unroll
  for (int j = 0; j < 32; j += 8)
    out[(size_t)(c0 + ty + j) * R + r0 + tx] = tile[tx][ty + j];
}

// ---------------------------------------------------------------- GEMM 8-phase
// Best-measured GEMM across 5 structural variants (r8/r11: 74.2-75.5us,
// MfmaUtil 27.5% — the session ceiling; per-wave 64x64/128x64, ring depth,
// occupancy, and swizzle variations all land 22-27.5%). GEMM1 + GEMM2.
// BM=256, BN=128, BK=64, 3-slot LDS ring (144 KiB), 512 threads = 8 waves
// (4M x 2N), per-wave 64x64. Per K-tile: 2 phases of {8 ds_read_b128 ->
// stage issue -> barrier -> lgkmcnt(0) -> setprio(1) 16 MFMA setprio(0) ->
// barrier}; counted vmcnt(6) at tile boundary only. XOR swizzle (0-conflict,
// measured r4/r6/r8/r11): stored chunk q^(row&7), pre-swizzled global source.
template <int MODE>
__global__ __launch_bounds__(512, 2) void gemm_8p(
    const bf16_t* __restrict__ A, const bf16_t* __restrict__ Bt,
    const float* __restrict__ bias, float* __restrict__ outf,
    bf16_t* __restrict__ out0, bf16_t* __restrict__ out1,
    bf16_t* __restrict__ out2, int M, int N, int K) {
  const int tid = threadIdx.x;        // 0..511
  const int lane = tid & 63;
  const int wave = tid >> 6;          // 0..7
  const int quad = lane >> 4;
  const int lr = lane & 15;
  const int wr = wave >> 1;           // 0..3 (M quarter, 64 rows)
  const int wc = wave & 1;            // 0..1 (N half, 64 cols)
  const int m0 = blockIdx.y * 256;
  const int n0 = blockIdx.x * 128;

  __shared__ __align__(16) bf16_t As[3][256 * 64];  // 96 KiB
  __shared__ __align__(16) bf16_t Bs[3][128 * 64];  // 48 KiB

  const f32x4 zero = {0.f, 0.f, 0.f, 0.f};
  f32x4 acc[4][4];
#pragma unroll
  for (int mi = 0; mi < 4; ++mi)
#pragma unroll
    for (int ni = 0; ni < 4; ++ni) acc[mi][ni] = zero;

  int ar[4], ac[4], br[2], bc[2];
#pragma unroll
  for (int i = 0; i < 4; ++i) {
    int c = tid + i * 512;
    ar[i] = c >> 3;
    ac[i] = ((c & 7) ^ (ar[i] & 7)) * 8;
  }
#pragma unroll
  for (int i = 0; i < 2; ++i) {
    int c = tid + i * 512;
    br[i] = c >> 3;
    bc[i] = ((c & 7) ^ (br[i] & 7)) * 8;
  }

  const int nk = K >> 6;

  auto stageA = [&](int t, int s) {
    const int ko = t << 6;
#pragma unroll
    for (int i = 0; i < 4; ++i)
      gld16(&A[(size_t)(m0 + ar[i]) * K + ko + ac[i]],
            &As[s][(tid + i * 512) * 8]);
  };
  auto stageB = [&](int t, int s) {
    const int ko = t << 6;
#pragma unroll
    for (int i = 0; i < 2; ++i)
      gld16(&Bt[(size_t)(n0 + br[i]) * K + ko + bc[i]],
            &Bs[s][(tid + i * 512) * 8]);
  };

  stageA(0, 0); stageB(0, 0);
  stageA(1, 1); stageB(1, 1);
  asm volatile("s_waitcnt vmcnt(6)" ::: "memory");
  __builtin_amdgcn_s_barrier();

  const int sx = lr & 7;
  const int arow = wr * 64 + lr;
  const int brow = wc * 64 + lr;

  int scur = 0;
  for (int t = 0; t < nk; ++t) {
    const bf16_t* as = As[scur];
    const bf16_t* bs = Bs[scur];
    int s2 = scur + 2;
    if (s2 >= 3) s2 -= 3;
    const bool pre = (t + 2 < nk);
#pragma unroll
    for (int ks = 0; ks < 2; ++ks) {
      bf16x8 af[4], bfr[4];
      const int cx = (((ks << 2) | quad) ^ sx) * 8;
#pragma unroll
      for (int mi = 0; mi < 4; ++mi)
        af[mi] = *(const bf16x8*)&as[(arow + mi * 16) * 64 + cx];
#pragma unroll
      for (int ni = 0; ni < 4; ++ni)
        bfr[ni] = *(const bf16x8*)&bs[(brow + ni * 16) * 64 + cx];
      if (ks == 0) {
        if (pre) stageA(t + 2, s2);
      } else {
        if (pre) stageB(t + 2, s2);
      }
      __builtin_amdgcn_s_barrier();
      asm volatile("s_waitcnt lgkmcnt(0)" ::: "memory");
      __builtin_amdgcn_sched_barrier(0);
      __builtin_amdgcn_s_setprio(1);
#pragma unroll
      for (int mi = 0; mi < 4; ++mi)
#pragma unroll
        for (int ni = 0; ni < 4; ++ni)
          acc[mi][ni] = __builtin_amdgcn_mfma_f32_16x16x32_bf16(
              af[mi], bfr[ni], acc[mi][ni], 0, 0, 0);
      __builtin_amdgcn_s_setprio(0);
      if (ks == 0) {
        __builtin_amdgcn_s_barrier();
      } else if (t + 1 < nk) {
        if (pre)
          asm volatile("s_waitcnt vmcnt(6)" ::: "memory");
        else
          asm volatile("s_waitcnt vmcnt(0)" ::: "memory");
        __builtin_amdgcn_s_barrier();
      }
    }
    scur = (scur == 2) ? 0 : scur + 1;
  }

  // Epilogue. C/D layout: col = lane&15, row = quad*4 + r.
#pragma unroll
  for (int mi = 0; mi < 4; ++mi) {
    const int mbase = m0 + wr * 64 + mi * 16 + quad * 4;
#pragma unroll
    for (int ni = 0; ni < 4; ++ni) {
      const int n = n0 + wc * 64 + ni * 16 + lr;
      const float bv = bias[n];
      if (MODE == 1) {
#pragma unroll
        for (int r = 0; r < 4; ++r)
          outf[(size_t)(mbase + r) * N + n] = acc[mi][ni][r] + bv;
      } else {
        const int which = n >> 10;
        const int h = (n >> 6) & 15;
        const int hd = n & 63;
        const int b = mbase >> 11;
        const int s = mbase & 2047;
        if (which == 2) {
          bf16x4 pk = {(bf16_t)(acc[mi][ni][0] + bv),
                       (bf16_t)(acc[mi][ni][1] + bv),
                       (bf16_t)(acc[mi][ni][2] + bv),
                       (bf16_t)(acc[mi][ni][3] + bv)};
          *(bf16x4*)&out2[(((size_t)(b * Hh + h)) * HDd + hd) * Ss + s] = pk;
        } else {
          bf16_t* dst = (which == 0) ? out0 : out1;
          const float sc2 = (which == 0) ? QSC : 1.0f;
#pragma unroll
          for (int r = 0; r < 4; ++r)
            dst[(((size_t)(b * Hh + h)) * Ss + s + r) * HDd + hd] =
                (bf16_t)((acc[mi][ni][r] + bv) * sc2);
        }
      }
    }
  }
}

// ---------------------------------------------------------------- attention
// r11 base (swizzled LDS, VALU l_run, shfl reduce) + THIS ROUND's change:
// kk2-interleaved softmax/PV. Dependency: PV chunk kk2 reads only P slices
// kt4 in {2kk2, 2kk2+1}. New order per ktile:
//   QK(16 MFMA) -> SM(kt4 0,1) -> Ps(0,1) -> PV(kk2=0, 8 MFMA)
//                -> SM(kt4 2,3) -> Ps(2,3) -> PV(kk2=1, 8 MFMA)
// The wave issues PV(0)'s MFMAs then runs SM(2,3)'s exp2 chain on the VALU
// while they drain — intra-wave MFMA/VALU overlap, halving the serial VALU
// exposure. No sync-structure change (same single barrier per ktile; the
// Ps round-trip stays same-wave with compiler lgkmcnt).
__global__ __launch_bounds__(256) void attn_kernel(
    const bf16_t* __restrict__ Qg, const bf16_t* __restrict__ Kg,
    const bf16_t* __restrict__ Vtg, bf16_t* __restrict__ Og) {
  const int tid = threadIdx.x;
  const int lane = tid & 63;
  const int wave = tid >> 6;
  const int quad = lane >> 4;
  const int lr = lane & 15;
  const int l7 = lr & 7;

  const int bid = blockIdx.x;        // 0..511
  const int xcd = bid & 7;
  const int j = bid >> 3;            // 0..63
  const int bh = xcd * 8 + (j >> 3); // 8 bh per XCD
  const int p = j & 7;               // pair index 0..7
  const int b = bh >> 4;
  const int h = bh & 15;
  const int wq = wave * 32;

  const bf16_t* Qp = Qg + (size_t)bh * Ss * HDd;   // [s][d] (pre-scaled)
  const bf16_t* Kp = Kg + (size_t)bh * Ss * HDd;   // [s][d]
  const bf16_t* Vp = Vtg + (size_t)bh * HDd * Ss;  // [d][s]

  __shared__ bf16_t Ks[2][64 * 64];    // [buf][key][d]   swizzled rows
  __shared__ bf16_t Vts[2][64 * 64];   // [buf][d][key]   swizzled rows
  __shared__ bf16_t Ps[4][32 * 64];    // per-wave P [q][key] swizzled rows

  bf16x8 kreg[2], vreg[2];
  const int r0 = tid >> 3;             // 0..31
  const int c0 = (tid & 7) * 8;        // 0..56
  const int swz = ((tid & 7) ^ ((tid >> 3) & 7)) * 8;

  const f32x4 zero = {0.f, 0.f, 0.f, 0.f};

#pragma unroll
  for (int i = 0; i < 2; ++i) {
    kreg[i] = *(const bf16x8*)&Kp[(size_t)(r0 + i * 32) * HDd + c0];
    vreg[i] = *(const bf16x8*)&Vp[(size_t)(r0 + i * 32) * Ss + c0];
  }

  int cur = 0;
  for (int half = 0; half < 2; ++half) {
    const int qt = half ? p : 15 - p;
    const int qbase = qt * 128;
    const int ktiles = qt * 2 + 2;

    bf16x8 bq[2][2];
#pragma unroll
    for (int qt2 = 0; qt2 < 2; ++qt2)
#pragma unroll
      for (int kk2 = 0; kk2 < 2; ++kk2)
        bq[qt2][kk2] = *(const bf16x8*)&Qp[(size_t)(qbase + wq + qt2 * 16 +
                                                    lr) *
                                               HDd +
                                           kk2 * 32 + quad * 8];

    f32x4 oacc[4][2];
#pragma unroll
    for (int dt = 0; dt < 4; ++dt)
#pragma unroll
      for (int qt2 = 0; qt2 < 2; ++qt2) oacc[dt][qt2] = zero;
    float l_run[2] = {0.f, 0.f};

    for (int kt = 0; kt < ktiles; ++kt) {
      const int kbase = kt * 64;

#pragma unroll
      for (int i = 0; i < 2; ++i) {
        *(bf16x8*)&Ks[cur][(r0 + i * 32) * 64 + swz] = kreg[i];
        *(bf16x8*)&Vts[cur][(r0 + i * 32) * 64 + swz] = vreg[i];
      }
      __syncthreads();

      const int nkb = (kt + 1 < ktiles) ? kbase + 64 : 0;
#pragma unroll
      for (int i = 0; i < 2; ++i) {
        kreg[i] = *(const bf16x8*)&Kp[(size_t)(nkb + r0 + i * 32) * HDd + c0];
        vreg[i] = *(const bf16x8*)&Vp[(size_t)(r0 + i * 32) * Ss + nkb + c0];
      }

      // QK^T: 16 MFMA, sacc[kt4] final after second kk2 pass
      f32x4 sacc[4][2];
#pragma unroll
      for (int kt4 = 0; kt4 < 4; ++kt4)
#pragma unroll
        for (int qt2 = 0; qt2 < 2; ++qt2) sacc[kt4][qt2] = zero;
#pragma unroll
      for (int kk2 = 0; kk2 < 2; ++kk2) {
        const int rsl = (((kk2 << 2) | quad) ^ l7) * 8;
        bf16x8 ak[4];
#pragma unroll
        for (int kt4 = 0; kt4 < 4; ++kt4)
          ak[kt4] = *(const bf16x8*)&Ks[cur][(kt4 * 16 + lr) * 64 + rsl];
#pragma unroll
        for (int kt4 = 0; kt4 < 4; ++kt4)
#pragma unroll
          for (int qt2 = 0; qt2 < 2; ++qt2)
            sacc[kt4][qt2] = __builtin_amdgcn_mfma_f32_16x16x32_bf16(
                ak[kt4], bq[qt2][kk2], sacc[kt4][qt2], 0, 0, 0);
      }

      const bool edge = (kt >= 2 * qt);
      // interleaved: SM slices {2kk2,2kk2+1} -> Ps -> PV(kk2); the exp2 of
      // slice pair 1 overlaps PV(0)'s in-flight MFMAs.
#pragma unroll
      for (int kk2 = 0; kk2 < 2; ++kk2) {
#pragma unroll
        for (int k4 = 0; k4 < 2; ++k4) {
          const int kt4 = kk2 * 2 + k4;
          const int psl = ((kt4 * 2 + (quad >> 1)) ^ l7) * 8 + (quad & 1) * 4;
#pragma unroll
          for (int qt2 = 0; qt2 < 2; ++qt2) {
#pragma unroll
            for (int r = 0; r < 4; ++r) {
              float s = sacc[kt4][qt2][r];
              if (edge) {
                const int qg = qbase + wq + qt2 * 16 + lr;
                const int kg = kbase + kt4 * 16 + quad * 4 + r;
                if (kg > qg) s = -1e30f;
              }
              const float pv = __builtin_amdgcn_exp2f(s);
              sacc[kt4][qt2][r] = pv;
              l_run[qt2] += pv;
            }
            bf16x4 pk = {(bf16_t)sacc[kt4][qt2][0], (bf16_t)sacc[kt4][qt2][1],
                         (bf16_t)sacc[kt4][qt2][2],
                         (bf16_t)sacc[kt4][qt2][3]};
            *(bf16x4*)&Ps[wave][(qt2 * 16 + lr) * 64 + psl] = pk;
          }
        }
        // PV chunk kk2 (needs only slices 2kk2, 2kk2+1, just written)
        const int rsl = (((kk2 << 2) | quad) ^ l7) * 8;
        bf16x8 av[4], bp[2];
#pragma unroll
        for (int dt = 0; dt < 4; ++dt)
          av[dt] = *(const bf16x8*)&Vts[cur][(dt * 16 + lr) * 64 + rsl];
#pragma unroll
        for (int qt2 = 0; qt2 < 2; ++qt2)
          bp[qt2] = *(const bf16x8*)&Ps[wave][(qt2 * 16 + lr) * 64 + rsl];
#pragma unroll
        for (int dt = 0; dt < 4; ++dt)
#pragma unroll
          for (int qt2 = 0; qt2 < 2; ++qt2)
            oacc[dt][qt2] = __builtin_amdgcn_mfma_f32_16x16x32_bf16(
                av[dt], bp[qt2], oacc[dt][qt2], 0, 0, 0);
      }
      cur ^= 1;
    }

#pragma unroll
    for (int qt2 = 0; qt2 < 2; ++qt2) {
      l_run[qt2] += __shfl_xor(l_run[qt2], 16, 64);
      l_run[qt2] += __shfl_xor(l_run[qt2], 32, 64);
    }

#pragma unroll
    for (int qt2 = 0; qt2 < 2; ++qt2) {
      const float inv = 1.f / l_run[qt2];
      const int qg = qbase + wq + qt2 * 16 + lr;
#pragma unroll
      for (int dt = 0; dt < 4; ++dt) {
        bf16x4 ov = {(bf16_t)(oacc[dt][qt2][0] * inv),
                     (bf16_t)(oacc[dt][qt2][1] * inv),
                     (bf16_t)(oacc[dt][qt2][2] * inv),
                     (bf16_t)(oacc[dt][qt2][3] * inv)};
        *(bf16x4*)&Og[((size_t)b * Ss + qg) * Dd + h * HDd + dt * 16 +
                      quad * 4] = ov;
      }
    }
  }
}

// ---------------------------------------------------------------- launch
extern "C" void kernel_launch(void* const* d_in, const int* in_sizes, int n_in,
                              void* d_out, int out_size, void* d_ws,
                              size_t ws_size, hipStream_t stream) {
  const float* x = (const float*)d_in[0];       // [4,2048,1024] fp32
  const float* w_qkv = (const float*)d_in[1];   // [1024,3072]
  const float* b_qkv = (const float*)d_in[2];   // [3072]
  const float* w_out = (const float*)d_in[3];   // [1024,1024]
  const float* b_out = (const float*)d_in[4];   // [1024]
  float* out = (float*)d_out;                   // [4,2048,1024] fp32 (32 MB)

  bf16_t* Kb = (bf16_t*)d_ws;                    // [B,H,S,HD] 16 MB
  bf16_t* Vt = Kb + (size_t)Bb * Hh * Ss * HDd;  // [B,H,HD,S] 16 MB
  bf16_t* slot3 = Vt + (size_t)Bb * Hh * Ss * HDd;
  bf16_t* Wt1 = slot3;                           // [3072,1024] 6 MB
  bf16_t* Ob = slot3;                            // [8192,1024] 16 MB
  bf16_t* Wt2 = Kb;                              // [1024,1024] 2 MB (post-attn)
  bf16_t* Qb = (bf16_t*)d_out;                   // [B,H,S,HD]
  bf16_t* Xc = (bf16_t*)d_out + (size_t)8192 * 1024;  // [8192,1024] bf16

  // fused conv + w_qkv transpose (8192 + 3072 blocks)
  prep<<<11264, 256, 0, stream>>>(x, Xc, w_qkv, Wt1);

  // GEMM1: 24x32 = 768 blocks = 3 exact rounds of 256 CUs.
  gemm_8p<0><<<dim3(24, 32), 512, 0, stream>>>(
      Xc, Wt1, b_qkv, nullptr, Qb, Kb, Vt, 8192, 3072, 1024);

  attn_kernel<<<dim3(512), 256, 0, stream>>>(Qb, Kb, Vt, Ob);

  transpose_conv<<<dim3(32, 32), dim3(32, 8), 0, stream>>>(w_out, Wt2, 1024,
                                                           1024);

  // GEMM2: 8x32 = 256 blocks = 1 per CU, uniform single round.
  gemm_8p<1><<<dim3(8, 32), 512, 0, stream>>>(
      Ob, Wt2, b_out, out, nullptr, nullptr, nullptr, 8192, 1024, 1024);
}